// Round 1
// baseline (203.758 us; speedup 1.0000x reference)
//
#include <hip/hip_runtime.h>
#include <stdint.h>

#define Bd 2
#define Td 2048
#define Cd 1024
#define Hd 16
#define HDd 64
#define BT 4096

typedef _Float16 f16;
typedef __attribute__((ext_vector_type(8))) _Float16 f16x8;
typedef __attribute__((ext_vector_type(4))) _Float16 f16x4;
typedef __attribute__((ext_vector_type(4))) float f32x4;

#define GLD_LDS16(gptr, lptr)                                                        \
    __builtin_amdgcn_global_load_lds((const __attribute__((address_space(1))) void*)(gptr), \
                                     (__attribute__((address_space(3))) void*)(lptr), 16, 0, 0)

// ---------------- trig tables: cos/sin of freqs (T x 32) ----------------
__global__ void k_trig(const float* __restrict__ freqs, float* __restrict__ cosT,
                       float* __restrict__ sinT) {
    int i = blockIdx.x * 256 + threadIdx.x;  // 65536 total
    float f = freqs[i];
    cosT[i] = cosf(f);
    sinT[i] = sinf(f);
}

// ---------------- f32 -> f16 conversion (q,k,v,Wq,Wk,Wv,Wo) ----------------
__global__ void k_cvt(const float* __restrict__ q, const float* __restrict__ k,
                      const float* __restrict__ v, const float* __restrict__ wq,
                      const float* __restrict__ wk, const float* __restrict__ wv,
                      const float* __restrict__ wo, f16* __restrict__ qh, f16* __restrict__ kh,
                      f16* __restrict__ vh, f16* __restrict__ wqh, f16* __restrict__ wkh,
                      f16* __restrict__ wvh, f16* __restrict__ woh) {
    int g = blockIdx.x * 256 + threadIdx.x;  // float4 groups, 4194304 total
    const float* src;
    f16* dst;
    int base;
    if (g < 1048576)      { src = q;  dst = qh;  base = 0; }
    else if (g < 2097152) { src = k;  dst = kh;  base = 1048576; }
    else if (g < 3145728) { src = v;  dst = vh;  base = 2097152; }
    else if (g < 3407872) { src = wq; dst = wqh; base = 3145728; }
    else if (g < 3670016) { src = wk; dst = wkh; base = 3407872; }
    else if (g < 3932160) { src = wv; dst = wvh; base = 3670016; }
    else                  { src = wo; dst = woh; base = 3932160; }
    int i = g - base;
    float4 val = reinterpret_cast<const float4*>(src)[i];
    f16x4 o;
    o[0] = (f16)val.x; o[1] = (f16)val.y; o[2] = (f16)val.z; o[3] = (f16)val.w;
    reinterpret_cast<f16x4*>(dst)[i] = o;
}

// ---------------- GEMM: out[m][n] = sum_k A[m][k] * W[n][k]  (M=4096,N=1024,K=1024)
template <int OUT_F32>
__device__ __forceinline__ void gemm_body(const f16* __restrict__ A, const f16* __restrict__ W,
                                          void* __restrict__ out) {
    __shared__ __attribute__((aligned(16))) f16 Alds[128 * 32];
    __shared__ __attribute__((aligned(16))) f16 Blds[128 * 32];
    const int tid = threadIdx.x;
    const int lane = tid & 63, w = tid >> 6;
    const int g = lane >> 4, r15 = lane & 15;
    const int m0 = blockIdx.y * 128, n0 = blockIdx.x * 128;
    const int wm = (w >> 1) * 64, wn = (w & 1) * 64;

    const f32x4 zero4 = {0.f, 0.f, 0.f, 0.f};
    f32x4 acc[4][4];
#pragma unroll
    for (int i = 0; i < 4; ++i) {
#pragma unroll
        for (int j = 0; j < 4; ++j) acc[i][j] = zero4;
    }

    const int srow = w * 32 + (lane >> 2);  // + c*16
    const int sch = (lane & 3) * 8;

    for (int k0 = 0; k0 < Cd; k0 += 32) {
#pragma unroll
        for (int c = 0; c < 2; ++c) {
            int row = srow + c * 16;
            GLD_LDS16(A + (m0 + row) * Cd + k0 + sch, &Alds[(w * 2 + c) * 512]);
            GLD_LDS16(W + (n0 + row) * Cd + k0 + sch, &Blds[(w * 2 + c) * 512]);
        }
        __syncthreads();
        f16x8 af[4], bf[4];
#pragma unroll
        for (int t = 0; t < 4; ++t) {
            af[t] = *(const f16x8*)&Alds[(wm + t * 16 + r15) * 32 + g * 8];
            bf[t] = *(const f16x8*)&Blds[(wn + t * 16 + r15) * 32 + g * 8];
        }
#pragma unroll
        for (int i = 0; i < 4; ++i) {
#pragma unroll
            for (int j = 0; j < 4; ++j)
                acc[i][j] = __builtin_amdgcn_mfma_f32_16x16x32_f16(af[i], bf[j], acc[i][j], 0, 0, 0);
        }
        __syncthreads();
    }
#pragma unroll
    for (int i = 0; i < 4; ++i) {
#pragma unroll
        for (int j = 0; j < 4; ++j) {
#pragma unroll
            for (int r = 0; r < 4; ++r) {
                int row = m0 + wm + i * 16 + g * 4 + r;
                int col = n0 + wn + j * 16 + r15;
                if (OUT_F32)
                    ((float*)out)[row * Cd + col] = acc[i][j][r];
                else
                    ((f16*)out)[row * Cd + col] = (f16)acc[i][j][r];
            }
        }
    }
}

__global__ __launch_bounds__(256) void k_gemm_qkv(const f16* qh, const f16* kh, const f16* vh,
                                                  const f16* wqh, const f16* wkh, const f16* wvh,
                                                  f16* Qp, f16* Kp, f16* Vp) {
    int z = blockIdx.z;
    const f16* A = (z == 0) ? qh : (z == 1) ? kh : vh;
    const f16* W = (z == 0) ? wqh : (z == 1) ? wkh : wvh;
    f16* out = (z == 0) ? Qp : (z == 1) ? Kp : Vp;
    gemm_body<0>(A, W, out);
}

__global__ __launch_bounds__(256) void k_gemm_out(const f16* yh, const f16* woh, float* out) {
    gemm_body<1>(yh, woh, out);
}

// ---------------- RoPE in-place on Qp, Kp ----------------
__global__ void k_rope(f16* __restrict__ Qp, f16* __restrict__ Kp, const float* __restrict__ cosT,
                       const float* __restrict__ sinT) {
    int idx = blockIdx.x * 256 + threadIdx.x;  // 2 * 524288
    f16* ptr = (idx < 524288) ? Qp : Kp;
    int i = idx & 524287;
    int gi = i & 7;     // 8-elem group within head dim
    int bth = i >> 3;   // bt*16 + h
    int h = bth & 15;
    int bt = bth >> 4;
    int t = bt & 2047;
    int off = bt * 1024 + h * 64 + gi * 8;
    f16x8 v = *(f16x8*)(ptr + off);
    float4 c4 = *(const float4*)&cosT[t * 32 + gi * 4];
    float4 s4 = *(const float4*)&sinT[t * 32 + gi * 4];
    f16x8 o;
    float x0, x1;
    x0 = (float)v[0]; x1 = (float)v[1];
    o[0] = (f16)(x0 * c4.x - x1 * s4.x); o[1] = (f16)(x0 * s4.x + x1 * c4.x);
    x0 = (float)v[2]; x1 = (float)v[3];
    o[2] = (f16)(x0 * c4.y - x1 * s4.y); o[3] = (f16)(x0 * s4.y + x1 * c4.y);
    x0 = (float)v[4]; x1 = (float)v[5];
    o[4] = (f16)(x0 * c4.z - x1 * s4.z); o[5] = (f16)(x0 * s4.z + x1 * c4.z);
    x0 = (float)v[6]; x1 = (float)v[7];
    o[6] = (f16)(x0 * c4.w - x1 * s4.w); o[7] = (f16)(x0 * s4.w + x1 * c4.w);
    *(f16x8*)(ptr + off) = o;
}

// ---------------- V transpose: Vp[bt][h*64+d] -> Vt[bh][d][t] ----------------
__global__ void k_vtrans(const f16* __restrict__ Vp, f16* __restrict__ Vt) {
    __shared__ __attribute__((aligned(16))) f16 tile[64][72];
    int bh = blockIdx.y, b = bh >> 4, h = bh & 15;
    int t0 = blockIdx.x * 64;
    int tid = threadIdx.x;
#pragma unroll
    for (int c = 0; c < 2; ++c) {
        int id = c * 256 + tid;
        int row = id >> 3, ch = id & 7;
        *(f16x8*)&tile[row][ch * 8] =
            *(const f16x8*)(Vp + (b * 2048 + t0 + row) * 1024 + h * 64 + ch * 8);
    }
    __syncthreads();
#pragma unroll
    for (int c = 0; c < 2; ++c) {
        int id = c * 256 + tid;
        int d = id & 63, tch = id >> 6;  // d = lane within wave -> conflict-free LDS reads
        f16x8 vv;
#pragma unroll
        for (int j = 0; j < 8; ++j) vv[j] = tile[tch * 8 + j][d];
        *(f16x8*)(Vt + (bh * 64 + d) * 2048 + t0 + tch * 8) = vv;
    }
}

// ---------------- Flash attention ----------------
// grid: x = q-tile (32), y = bh (32). 256 threads = 4 waves x 16 q-rows.
__global__ __launch_bounds__(256, 2) void k_flash(const f16* __restrict__ Qp,
                                                  const f16* __restrict__ Kp,
                                                  const f16* __restrict__ Vt,
                                                  f16* __restrict__ y) {
    __shared__ __attribute__((aligned(16))) f16 Klds[64 * 64];
    __shared__ __attribute__((aligned(16))) f16 Vlds[64 * 64];
    __shared__ __attribute__((aligned(16))) f16 Plds[4 * 64 * 20];  // per-wave P^T [64][20-padded 16]
    const int bh = blockIdx.y, b = bh >> 4, h = bh & 15;
    const int q0 = blockIdx.x * 64;
    const int tid = threadIdx.x, lane = tid & 63, w = tid >> 6;
    const int g = lane >> 4, r15 = lane & 15;
    f16* myP = &Plds[w * 1280];

    // Q fragments, exact *0.125 (power of 2) folds the 1/sqrt(HD) score scale
    f16x8 qf[2];
    {
        const f16* qb = Qp + (b * 2048 + q0 + w * 16 + r15) * 1024 + h * 64;
#pragma unroll
        for (int ks = 0; ks < 2; ++ks) {
            f16x8 v = *(const f16x8*)(qb + ks * 32 + g * 8);
#pragma unroll
            for (int j = 0; j < 8; ++j) v[j] = (f16)((float)v[j] * 0.125f);
            qf[ks] = v;
        }
    }
    const f32x4 zero4 = {0.f, 0.f, 0.f, 0.f};
    f32x4 o[4];
#pragma unroll
    for (int i = 0; i < 4; ++i) o[i] = zero4;
    f32x4 mrow = {-1e30f, -1e30f, -1e30f, -1e30f};
    f32x4 lrow = zero4;

    for (int s0 = 0; s0 < 2048; s0 += 64) {
        __syncthreads();  // previous iteration's LDS reads done
#pragma unroll
        for (int c = 0; c < 2; ++c) {
            int row = c * 32 + (tid >> 3);
            int ch = tid & 7;
            int chs = ch ^ (row & 7);  // XOR swizzle: kills 16-way bank conflict on frag reads
            *(f16x8*)&Klds[row * 64 + chs * 8] =
                *(const f16x8*)(Kp + (b * 2048 + s0 + row) * 1024 + h * 64 + ch * 8);
            *(f16x8*)&Vlds[row * 64 + chs * 8] =
                *(const f16x8*)(Vt + (bh * 64 + row) * 2048 + s0 + ch * 8);
        }
        __syncthreads();
        // S = (Q*0.125) K^T : 4 s-tiles x 2 k-steps
        f32x4 s[4];
#pragma unroll
        for (int st = 0; st < 4; ++st) s[st] = zero4;
#pragma unroll
        for (int st = 0; st < 4; ++st) {
            int krow = st * 16 + r15;
#pragma unroll
            for (int ks = 0; ks < 2; ++ks) {
                f16x8 kf = *(const f16x8*)&Klds[krow * 64 + (((ks << 2) | g) ^ (krow & 7)) * 8];
                s[st] = __builtin_amdgcn_mfma_f32_16x16x32_f16(qf[ks], kf, s[st], 0, 0, 0);
            }
        }
        // wave-parallel row max over 16 lanes (cols) and 4 s-tiles
        f32x4 pm;
#pragma unroll
        for (int r = 0; r < 4; ++r)
            pm[r] = fmaxf(fmaxf(s[0][r], s[1][r]), fmaxf(s[2][r], s[3][r]));
#pragma unroll
        for (int d = 1; d < 16; d <<= 1) {
#pragma unroll
            for (int r = 0; r < 4; ++r) pm[r] = fmaxf(pm[r], __shfl_xor(pm[r], d, 64));
        }
        f32x4 corr;
#pragma unroll
        for (int r = 0; r < 4; ++r) {
            float mn = fmaxf(mrow[r], pm[r]);
            corr[r] = __expf(mrow[r] - mn);
            mrow[r] = mn;
        }
        // P = exp(S - m), write P^T to LDS, row-sum
        f32x4 rs = zero4;
#pragma unroll
        for (int st = 0; st < 4; ++st) {
            f16x4 pv;
#pragma unroll
            for (int r = 0; r < 4; ++r) {
                float p = __expf(s[st][r] - mrow[r]);
                rs[r] += p;
                pv[r] = (f16)p;
            }
            *(f16x4*)&myP[(st * 16 + r15) * 20 + g * 4] = pv;
        }
#pragma unroll
        for (int d = 1; d < 16; d <<= 1) {
#pragma unroll
            for (int r = 0; r < 4; ++r) rs[r] += __shfl_xor(rs[r], d, 64);
        }
#pragma unroll
        for (int r = 0; r < 4; ++r) lrow[r] = lrow[r] * corr[r] + rs[r];
#pragma unroll
        for (int dt = 0; dt < 4; ++dt) {
#pragma unroll
            for (int r = 0; r < 4; ++r) o[dt][r] *= corr[r];
        }
        // O += P V
#pragma unroll
        for (int ks = 0; ks < 2; ++ks) {
            f16x8 pa;
#pragma unroll
            for (int j = 0; j < 8; ++j) pa[j] = myP[(ks * 32 + g * 8 + j) * 20 + r15];
#pragma unroll
            for (int dt = 0; dt < 4; ++dt) {
                int vrow = dt * 16 + r15;
                f16x8 vf = *(const f16x8*)&Vlds[vrow * 64 + (((ks << 2) | g) ^ (vrow & 7)) * 8];
                o[dt] = __builtin_amdgcn_mfma_f32_16x16x32_f16(pa, vf, o[dt], 0, 0, 0);
            }
        }
    }
    // epilogue: normalize, store
#pragma unroll
    for (int r = 0; r < 4; ++r) {
        float inv = 1.0f / lrow[r];
        int row = b * 2048 + q0 + w * 16 + g * 4 + r;
#pragma unroll
        for (int dt = 0; dt < 4; ++dt) {
            y[row * 1024 + h * 64 + dt * 16 + r15] = (f16)(o[dt][r] * inv);
        }
    }
}

extern "C" void kernel_launch(void* const* d_in, const int* in_sizes, int n_in, void* d_out,
                              int out_size, void* d_ws, size_t ws_size, hipStream_t stream) {
    const float* q = (const float*)d_in[0];
    const float* k = (const float*)d_in[1];
    const float* v = (const float*)d_in[2];
    const float* fr = (const float*)d_in[3];
    const float* wq = (const float*)d_in[4];
    const float* wk = (const float*)d_in[5];
    const float* wv = (const float*)d_in[6];
    const float* wo = (const float*)d_in[7];
    char* ws = (char*)d_ws;

    float* cosT = (float*)(ws + 0);
    float* sinT = (float*)(ws + 262144);
    f16* qh = (f16*)(ws + 524288);
    f16* kh = (f16*)(ws + 8912896);
    f16* vh = (f16*)(ws + 17301504);
    f16* wqh = (f16*)(ws + 25690112);
    f16* wkh = (f16*)(ws + 27787264);
    f16* wvh = (f16*)(ws + 29884416);
    f16* woh = (f16*)(ws + 31981568);
    f16* Qp = (f16*)(ws + 34078720);
    f16* Kp = (f16*)(ws + 42467328);
    f16* Vp = (f16*)(ws + 50855936);
    // qh/kh are dead after the QKV GEMM: alias Vt and y over them
    f16* Vt = (f16*)(ws + 524288);
    f16* yh = (f16*)(ws + 8912896);

    k_trig<<<256, 256, 0, stream>>>(fr, cosT, sinT);
    k_cvt<<<16384, 256, 0, stream>>>(q, k, v, wq, wk, wv, wo, qh, kh, vh, wqh, wkh, wvh, woh);
    dim3 gq(8, 32, 3);
    k_gemm_qkv<<<gq, 256, 0, stream>>>(qh, kh, vh, wqh, wkh, wvh, Qp, Kp, Vp);
    k_rope<<<4096, 256, 0, stream>>>(Qp, Kp, cosT, sinT);
    dim3 gt(32, 32);
    k_vtrans<<<gt, 256, 0, stream>>>(Vp, Vt);
    dim3 gf(32, 32);
    k_flash<<<gf, 256, 0, stream>>>(Qp, Kp, Vt, yh);
    dim3 go(8, 32);
    k_gemm_out<<<go, 256, 0, stream>>>(yh, woh, (float*)d_out);
}

// Round 2
// 170.507 us; speedup vs baseline: 1.1950x; 1.1950x over previous
//
#include <hip/hip_runtime.h>
#include <stdint.h>

#define Bd 2
#define Td 2048
#define Cd 1024
#define Hd 16
#define HDd 64
#define BT 4096

typedef _Float16 f16;
typedef __attribute__((ext_vector_type(8))) _Float16 f16x8;
typedef __attribute__((ext_vector_type(4))) _Float16 f16x4;
typedef __attribute__((ext_vector_type(2))) _Float16 f16x2;
typedef __attribute__((ext_vector_type(4))) float f32x4;
typedef __attribute__((ext_vector_type(16))) float f32x16;

#define GLD_LDS16(gptr, lptr)                                                        \
    __builtin_amdgcn_global_load_lds((const __attribute__((address_space(1))) void*)(gptr), \
                                     (__attribute__((address_space(3))) void*)(lptr), 16, 0, 0)

// ---------------- trig tables: cos/sin of freqs (T x 32) ----------------
__global__ void k_trig(const float* __restrict__ freqs, float* __restrict__ cosT,
                       float* __restrict__ sinT) {
    int i = blockIdx.x * 256 + threadIdx.x;  // 65536 total
    float f = freqs[i];
    cosT[i] = cosf(f);
    sinT[i] = sinf(f);
}

// ---------------- f32 -> f16 conversion (q,k,v,Wq,Wk,Wv,Wo) ----------------
__global__ void k_cvt(const float* __restrict__ q, const float* __restrict__ k,
                      const float* __restrict__ v, const float* __restrict__ wq,
                      const float* __restrict__ wk, const float* __restrict__ wv,
                      const float* __restrict__ wo, f16* __restrict__ qh, f16* __restrict__ kh,
                      f16* __restrict__ vh, f16* __restrict__ wqh, f16* __restrict__ wkh,
                      f16* __restrict__ wvh, f16* __restrict__ woh) {
    int g = blockIdx.x * 256 + threadIdx.x;  // float4 groups, 4194304 total
    const float* src;
    f16* dst;
    int base;
    if (g < 1048576)      { src = q;  dst = qh;  base = 0; }
    else if (g < 2097152) { src = k;  dst = kh;  base = 1048576; }
    else if (g < 3145728) { src = v;  dst = vh;  base = 2097152; }
    else if (g < 3407872) { src = wq; dst = wqh; base = 3145728; }
    else if (g < 3670016) { src = wk; dst = wkh; base = 3407872; }
    else if (g < 3932160) { src = wv; dst = wvh; base = 3670016; }
    else                  { src = wo; dst = woh; base = 3932160; }
    int i = g - base;
    float4 val = reinterpret_cast<const float4*>(src)[i];
    f16x4 o;
    o[0] = (f16)val.x; o[1] = (f16)val.y; o[2] = (f16)val.z; o[3] = (f16)val.w;
    reinterpret_cast<f16x4*>(dst)[i] = o;
}

// ---------------- GEMM: out[m][n] = sum_k A[m][k] * W[n][k]  (M=4096,N=1024,K=1024)
template <int OUT_F32>
__device__ __forceinline__ void gemm_body(const f16* __restrict__ A, const f16* __restrict__ W,
                                          void* __restrict__ out) {
    __shared__ __attribute__((aligned(16))) f16 Alds[128 * 32];
    __shared__ __attribute__((aligned(16))) f16 Blds[128 * 32];
    const int tid = threadIdx.x;
    const int lane = tid & 63, w = tid >> 6;
    const int g = lane >> 4, r15 = lane & 15;
    const int m0 = blockIdx.y * 128, n0 = blockIdx.x * 128;
    const int wm = (w >> 1) * 64, wn = (w & 1) * 64;

    const f32x4 zero4 = {0.f, 0.f, 0.f, 0.f};
    f32x4 acc[4][4];
#pragma unroll
    for (int i = 0; i < 4; ++i) {
#pragma unroll
        for (int j = 0; j < 4; ++j) acc[i][j] = zero4;
    }

    const int srow = w * 32 + (lane >> 2);  // + c*16
    const int sch = (lane & 3) * 8;

    for (int k0 = 0; k0 < Cd; k0 += 32) {
#pragma unroll
        for (int c = 0; c < 2; ++c) {
            int row = srow + c * 16;
            GLD_LDS16(A + (m0 + row) * Cd + k0 + sch, &Alds[(w * 2 + c) * 512]);
            GLD_LDS16(W + (n0 + row) * Cd + k0 + sch, &Blds[(w * 2 + c) * 512]);
        }
        __syncthreads();
        f16x8 af[4], bf[4];
#pragma unroll
        for (int t = 0; t < 4; ++t) {
            af[t] = *(const f16x8*)&Alds[(wm + t * 16 + r15) * 32 + g * 8];
            bf[t] = *(const f16x8*)&Blds[(wn + t * 16 + r15) * 32 + g * 8];
        }
#pragma unroll
        for (int i = 0; i < 4; ++i) {
#pragma unroll
            for (int j = 0; j < 4; ++j)
                acc[i][j] = __builtin_amdgcn_mfma_f32_16x16x32_f16(af[i], bf[j], acc[i][j], 0, 0, 0);
        }
        __syncthreads();
    }
#pragma unroll
    for (int i = 0; i < 4; ++i) {
#pragma unroll
        for (int j = 0; j < 4; ++j) {
#pragma unroll
            for (int r = 0; r < 4; ++r) {
                int row = m0 + wm + i * 16 + g * 4 + r;
                int col = n0 + wn + j * 16 + r15;
                if (OUT_F32)
                    ((float*)out)[row * Cd + col] = acc[i][j][r];
                else
                    ((f16*)out)[row * Cd + col] = (f16)acc[i][j][r];
            }
        }
    }
}

__global__ __launch_bounds__(256) void k_gemm_qkv(const f16* qh, const f16* kh, const f16* vh,
                                                  const f16* wqh, const f16* wkh, const f16* wvh,
                                                  f16* Qp, f16* Kp, f16* Vp) {
    int z = blockIdx.z;
    const f16* A = (z == 0) ? qh : (z == 1) ? kh : vh;
    const f16* W = (z == 0) ? wqh : (z == 1) ? wkh : wvh;
    f16* out = (z == 0) ? Qp : (z == 1) ? Kp : Vp;
    gemm_body<0>(A, W, out);
}

__global__ __launch_bounds__(256) void k_gemm_out(const f16* yh, const f16* woh, float* out) {
    gemm_body<1>(yh, woh, out);
}

// ---------------- RoPE in-place on Qp, Kp ----------------
__global__ void k_rope(f16* __restrict__ Qp, f16* __restrict__ Kp, const float* __restrict__ cosT,
                       const float* __restrict__ sinT) {
    int idx = blockIdx.x * 256 + threadIdx.x;  // 2 * 524288
    f16* ptr = (idx < 524288) ? Qp : Kp;
    int i = idx & 524287;
    int gi = i & 7;     // 8-elem group within head dim
    int bth = i >> 3;   // bt*16 + h
    int h = bth & 15;
    int bt = bth >> 4;
    int t = bt & 2047;
    int off = bt * 1024 + h * 64 + gi * 8;
    f16x8 v = *(f16x8*)(ptr + off);
    float4 c4 = *(const float4*)&cosT[t * 32 + gi * 4];
    float4 s4 = *(const float4*)&sinT[t * 32 + gi * 4];
    f16x8 o;
    float x0, x1;
    x0 = (float)v[0]; x1 = (float)v[1];
    o[0] = (f16)(x0 * c4.x - x1 * s4.x); o[1] = (f16)(x0 * s4.x + x1 * c4.x);
    x0 = (float)v[2]; x1 = (float)v[3];
    o[2] = (f16)(x0 * c4.y - x1 * s4.y); o[3] = (f16)(x0 * s4.y + x1 * c4.y);
    x0 = (float)v[4]; x1 = (float)v[5];
    o[4] = (f16)(x0 * c4.z - x1 * s4.z); o[5] = (f16)(x0 * s4.z + x1 * c4.z);
    x0 = (float)v[6]; x1 = (float)v[7];
    o[6] = (f16)(x0 * c4.w - x1 * s4.w); o[7] = (f16)(x0 * s4.w + x1 * c4.w);
    *(f16x8*)(ptr + off) = o;
}

// ---------------- V transpose: Vp[bt][h*64+d] -> Vt[bh][d][t] ----------------
__global__ void k_vtrans(const f16* __restrict__ Vp, f16* __restrict__ Vt) {
    __shared__ __attribute__((aligned(16))) f16 tile[64][72];
    int bh = blockIdx.y, b = bh >> 4, h = bh & 15;
    int t0 = blockIdx.x * 64;
    int tid = threadIdx.x;
#pragma unroll
    for (int c = 0; c < 2; ++c) {
        int id = c * 256 + tid;
        int row = id >> 3, ch = id & 7;
        *(f16x8*)&tile[row][ch * 8] =
            *(const f16x8*)(Vp + (b * 2048 + t0 + row) * 1024 + h * 64 + ch * 8);
    }
    __syncthreads();
#pragma unroll
    for (int c = 0; c < 2; ++c) {
        int id = c * 256 + tid;
        int d = id & 63, tch = id >> 6;  // d = lane within wave -> conflict-free LDS reads
        f16x8 vv;
#pragma unroll
        for (int j = 0; j < 8; ++j) vv[j] = tile[tch * 8 + j][d];
        *(f16x8*)(Vt + (bh * 64 + d) * 2048 + t0 + tch * 8) = vv;
    }
}

// ---------------- Flash attention, swapped-QK^T 32x32 structure ----------------
// grid: x = q-superblock (8 x 256 rows), y = bh (32). 512 threads = 8 waves x 32 q-rows.
// S^T = mfma(K, Q): lane owns q-col = lane&31; kv rows live in regs -> in-register softmax.
__global__ __launch_bounds__(512, 2) void k_flash(const f16* __restrict__ Qp,
                                                  const f16* __restrict__ Kp,
                                                  const f16* __restrict__ Vt,
                                                  f16* __restrict__ y) {
    __shared__ __attribute__((aligned(16))) f16 Klds[2 * 2048];  // [buf][32 kv][64 d] swizzled
    __shared__ __attribute__((aligned(16))) f16 Vlds[2 * 2048];  // [buf][64 d][32 kv] swizzled
    const int bh = blockIdx.y, b = bh >> 4, h = bh & 15;
    const int tid = threadIdx.x, lane = tid & 63, w = tid >> 6;
    const int r31 = lane & 31, hi = lane >> 5;

    // --- staging assignment: waves 0-3 stage K (256 slots), waves 4-7 stage V (256 slots).
    // LDS is written linearly (slot*16B); the XOR swizzle is applied to the GLOBAL source
    // chunk so frag reads below can use the same XOR (m173 both-sides pattern).
    const f16* gsrc;
    f16* lbase;
    int gstep;
    if (tid < 256) {
        int row = tid >> 3;                 // kv row 0..31
        int ch = (tid & 7) ^ (row & 7);     // source d-chunk (8 f16)
        gsrc = Kp + (b * 2048 + row) * 1024 + h * 64 + ch * 8;
        gstep = 32 * 1024;                  // advance 32 kv rows per tile
        lbase = (f16*)Klds + w * 512;
    } else {
        int s = tid - 256;
        int d = s >> 2;                     // d row 0..63
        int cv = (s & 3) ^ ((d >> 1) & 3);  // source kv-chunk (8 f16)
        gsrc = Vt + (bh * 64 + d) * 2048 + cv * 8;
        gstep = 32;                         // advance 32 kv per tile
        lbase = (f16*)Vlds + (w - 4) * 512;
    }

    // --- Q fragments in registers: B-operand of mfma(K,Q). lane holds Q[q=r31][k=dc*16+hi*8+j]
    // exact *0.125 folds the 1/sqrt(HD) score scale (power of 2, no f16 rounding)
    f16x8 qf[4];
    {
        const f16* qb = Qp + (b * 2048 + blockIdx.x * 256 + w * 32 + r31) * 1024 + h * 64 + hi * 8;
        const f16 sc = (f16)0.125f;
#pragma unroll
        for (int dc = 0; dc < 4; ++dc) {
            f16x8 v = *(const f16x8*)(qb + dc * 16);
#pragma unroll
            for (int j = 0; j < 8; ++j) v[j] = v[j] * sc;
            qf[dc] = v;
        }
    }

    f32x16 o[2];
#pragma unroll
    for (int t2 = 0; t2 < 2; ++t2) {
#pragma unroll
        for (int r = 0; r < 16; ++r) o[t2][r] = 0.f;
    }
    float m = -1e30f, l = 0.f;

    // prologue: stage tile 0
    GLD_LDS16(gsrc, lbase);
    __syncthreads();
    int cur = 0;
    for (int t = 0; t < 64; ++t) {
        if (t < 63) GLD_LDS16(gsrc + (t + 1) * gstep, lbase + (cur ^ 1) * 2048);
        const f16* Kl = (const f16*)Klds + cur * 2048;
        const f16* Vl = (const f16*)Vlds + cur * 2048;
        // S^T[kv][q] : A = K (row=kv=r31, k=d chunk), B = Q^T (regs)
        f32x16 sA;
#pragma unroll
        for (int r = 0; r < 16; ++r) sA[r] = 0.f;
#pragma unroll
        for (int dc = 0; dc < 4; ++dc) {
            f16x8 kf = *(const f16x8*)&Kl[r31 * 64 + ((2 * dc + hi) ^ (r31 & 7)) * 8];
            sA = __builtin_amdgcn_mfma_f32_32x32x16_f16(kf, qf[dc], sA, 0, 0, 0);
        }
        // in-register online softmax: lane holds S[kv=(r&3)+8*(r>>2)+4*hi][q=r31], r=0..15
        float t8[8];
#pragma unroll
        for (int r = 0; r < 8; ++r) t8[r] = fmaxf(sA[r], sA[r + 8]);
#pragma unroll
        for (int r = 0; r < 4; ++r) t8[r] = fmaxf(t8[r], t8[r + 4]);
        float pmax = fmaxf(fmaxf(t8[0], t8[1]), fmaxf(t8[2], t8[3]));
        pmax = fmaxf(pmax, __shfl_xor(pmax, 32, 64));  // union with partner half's kv set
        float mnew = fmaxf(m, pmax);
        float corr = __expf(m - mnew);
        m = mnew;
        float rs = 0.f;
#pragma unroll
        for (int r = 0; r < 16; ++r) {
            float pv = __expf(sA[r] - m);
            sA[r] = pv;
            rs += pv;
        }
        rs += __shfl_xor(rs, 32, 64);
        l = l * corr + rs;
#pragma unroll
        for (int r = 0; r < 16; ++r) { o[0][r] *= corr; o[1][r] *= corr; }
        // pack P to f16 pairs; partner-exchange builds PV's B-operand in-register
        unsigned int pk[8], xk[8];
#pragma unroll
        for (int i = 0; i < 8; ++i) {
            union { f16x2 h2; unsigned int u; } cv;
            cv.h2[0] = (f16)sA[2 * i];
            cv.h2[1] = (f16)sA[2 * i + 1];
            pk[i] = cv.u;
        }
#pragma unroll
        for (int i = 0; i < 8; ++i) xk[i] = (unsigned int)__shfl_xor((int)pk[i], 32, 64);
        f16x8 bfr[2];
        {
            union { unsigned int u[4]; f16x8 v; } uv;
            uv.u[0] = hi ? xk[2] : pk[0];
            uv.u[1] = hi ? xk[3] : pk[1];
            uv.u[2] = hi ? pk[2] : xk[0];
            uv.u[3] = hi ? pk[3] : xk[1];
            bfr[0] = uv.v;
            uv.u[0] = hi ? xk[6] : pk[4];
            uv.u[1] = hi ? xk[7] : pk[5];
            uv.u[2] = hi ? pk[6] : xk[4];
            uv.u[3] = hi ? pk[7] : xk[5];
            bfr[1] = uv.v;
        }
        // O^T[d][q] += V^T[d][kv] P[kv][q] : A = V^T tile, B = P
#pragma unroll
        for (int s = 0; s < 2; ++s) {
#pragma unroll
            for (int t2 = 0; t2 < 2; ++t2) {
                f16x8 vf = *(const f16x8*)&Vl[(t2 * 32 + r31) * 32 +
                                              ((2 * s + hi) ^ ((r31 >> 1) & 3)) * 8];
                o[t2] = __builtin_amdgcn_mfma_f32_32x32x16_f16(vf, bfr[s], o[t2], 0, 0, 0);
            }
        }
        __syncthreads();  // also drains vmcnt: next tile staged, this tile's reads done
        cur ^= 1;
    }
    // epilogue: lane holds O^T[d=(r&3)+8*(r>>2)+4*hi+32*t2][q=r31]; normalize + store
    float inv = 1.0f / l;
    f16* yb = y + (b * 2048 + blockIdx.x * 256 + w * 32 + r31) * 1024 + h * 64 + hi * 4;
#pragma unroll
    for (int t2 = 0; t2 < 2; ++t2) {
#pragma unroll
        for (int rg = 0; rg < 4; ++rg) {
            f16x4 ov;
#pragma unroll
            for (int i = 0; i < 4; ++i) ov[i] = (f16)(o[t2][rg * 4 + i] * inv);
            *(f16x4*)&yb[t2 * 32 + rg * 8] = ov;
        }
    }
}

extern "C" void kernel_launch(void* const* d_in, const int* in_sizes, int n_in, void* d_out,
                              int out_size, void* d_ws, size_t ws_size, hipStream_t stream) {
    const float* q = (const float*)d_in[0];
    const float* k = (const float*)d_in[1];
    const float* v = (const float*)d_in[2];
    const float* fr = (const float*)d_in[3];
    const float* wq = (const float*)d_in[4];
    const float* wk = (const float*)d_in[5];
    const float* wv = (const float*)d_in[6];
    const float* wo = (const float*)d_in[7];
    char* ws = (char*)d_ws;

    float* cosT = (float*)(ws + 0);
    float* sinT = (float*)(ws + 262144);
    f16* qh = (f16*)(ws + 524288);
    f16* kh = (f16*)(ws + 8912896);
    f16* vh = (f16*)(ws + 17301504);
    f16* wqh = (f16*)(ws + 25690112);
    f16* wkh = (f16*)(ws + 27787264);
    f16* wvh = (f16*)(ws + 29884416);
    f16* woh = (f16*)(ws + 31981568);
    f16* Qp = (f16*)(ws + 34078720);
    f16* Kp = (f16*)(ws + 42467328);
    f16* Vp = (f16*)(ws + 50855936);
    // qh/kh are dead after the QKV GEMM: alias Vt and y over them
    f16* Vt = (f16*)(ws + 524288);
    f16* yh = (f16*)(ws + 8912896);

    k_trig<<<256, 256, 0, stream>>>(fr, cosT, sinT);
    k_cvt<<<16384, 256, 0, stream>>>(q, k, v, wq, wk, wv, wo, qh, kh, vh, wqh, wkh, wvh, woh);
    dim3 gq(8, 32, 3);
    k_gemm_qkv<<<gq, 256, 0, stream>>>(qh, kh, vh, wqh, wkh, wvh, Qp, Kp, Vp);
    k_rope<<<4096, 256, 0, stream>>>(Qp, Kp, cosT, sinT);
    dim3 gt(32, 32);
    k_vtrans<<<gt, 256, 0, stream>>>(Vp, Vt);
    dim3 gf(8, 32);
    k_flash<<<gf, 512, 0, stream>>>(Qp, Kp, Vt, yh);
    dim3 go(8, 32);
    k_gemm_out<<<go, 256, 0, stream>>>(yh, woh, (float*)d_out);
}